// Round 1
// baseline (382.175 us; speedup 1.0000x reference)
//
#include <hip/hip_runtime.h>
#include <math.h>

#define HH 512
#define WW 512
#define NB 8
#define NN 256
#define KR 6
#define KS 13

__constant__ float c_unused; // none

__device__ __forceinline__ float bilerp_img(const float* __restrict__ img, float r, float c) {
    r = fminf(fmaxf(r, 0.f), (float)(HH - 1));
    c = fminf(fmaxf(c, 0.f), (float)(WW - 1));
    float rf = floorf(r), cf = floorf(c);
    int r0 = (int)rf, c0 = (int)cf;
    int r1 = min(r0 + 1, HH - 1), c1 = min(c0 + 1, WW - 1);
    float fr = r - rf, fc = c - cf;
    float v00 = img[r0 * WW + c0];
    float v01 = img[r0 * WW + c1];
    float v10 = img[r1 * WW + c0];
    float v11 = img[r1 * WW + c1];
    return v00 * (1.f - fr) * (1.f - fc) + v10 * fr * (1.f - fc)
         + v01 * (1.f - fr) * fc + v11 * fr * fc;
}

// ---------------- conv: separable 13x13 Gaussian-derivative, x10 ----------------
// tile 32x32 output, 256 threads. gimg layout [B][2][H][W].
__global__ __launch_bounds__(256) void conv_kernel(const float* __restrict__ pred,
                                                   float* __restrict__ gimg) {
    __shared__ float tin[32 + 2 * KR][32 + 2 * KR];   // 44x44
    __shared__ float midG[32 + 2 * KR][32];           // horizontal conv with g
    __shared__ float midD[32 + 2 * KR][32];           // horizontal conv with dg

    const int b  = blockIdx.z;
    const int ty0 = blockIdx.y * 32;
    const int tx0 = blockIdx.x * 32;
    const int t  = threadIdx.x;

    // filters (recomputed per thread; one-time cost)
    float g[KS], dg[KS];
    float s = 0.f;
#pragma unroll
    for (int i = 0; i < KS; ++i) {
        float x = (float)(i - KR);
        g[i] = expf(-x * x / (2.f * 2.f * 2.f));  // std=2 -> 2*std^2 = 8
        s += g[i];
    }
#pragma unroll
    for (int i = 0; i < KS; ++i) {
        g[i] /= s;
        dg[i] = (-(float)(i - KR) / 4.f) * g[i];  // -x/std^2 * g
    }

    const float* img = pred + (size_t)b * HH * WW;

    // load 44x44 input tile with zero padding
    for (int idx = t; idx < 44 * 44; idx += 256) {
        int ly = idx / 44, lx = idx % 44;
        int gy = ty0 + ly - KR, gx = tx0 + lx - KR;
        float v = 0.f;
        if (gy >= 0 && gy < HH && gx >= 0 && gx < WW) v = img[gy * WW + gx];
        tin[ly][lx] = v;
    }
    __syncthreads();

    // horizontal pass: 44 rows x 32 cols
    for (int idx = t; idx < 44 * 32; idx += 256) {
        int ly = idx / 32, ox = idx % 32;
        float aG = 0.f, aD = 0.f;
#pragma unroll
        for (int k = 0; k < KS; ++k) {
            float v = tin[ly][ox + k];
            aG += v * g[k];
            aD += v * dg[k];
        }
        midG[ly][ox] = aG;
        midD[ly][ox] = aD;
    }
    __syncthreads();

    // vertical pass: 32x32 outputs
    float* out0 = gimg + ((size_t)b * 2 + 0) * HH * WW;
    float* out1 = gimg + ((size_t)b * 2 + 1) * HH * WW;
    for (int idx = t; idx < 32 * 32; idx += 256) {
        int oy = idx / 32, ox = idx % 32;
        float a0 = 0.f, a1 = 0.f;
#pragma unroll
        for (int k = 0; k < KS; ++k) {
            a0 += midG[oy + k][ox] * dg[k];  // channel0: dg along rows, g along cols
            a1 += midD[oy + k][ox] * g[k];   // channel1: g along rows, dg along cols
        }
        int gy = ty0 + oy, gx = tx0 + ox;
        out0[gy * WW + gx] = 10.f * a0;
        out1[gy * WW + gx] = 10.f * a1;
    }
}

// ---------------- snake optimization: 20 implicit steps via Neumann series ----------------
// one block per batch, thread n = node n. M*q = q - Xq + X^2 q - X^3 q + X^4 q,
// X = stepsz*(alpha*D + beta*D^2), ||X|| <= 0.02 -> truncation ~3e-9 rel.
__global__ __launch_bounds__(256) void snake_kernel(const float* __restrict__ gimg,
                                                    const float* __restrict__ node_pos,
                                                    float* __restrict__ pos_out) {
    const int b = blockIdx.x;
    const int n = threadIdx.x;
    const float* g0 = gimg + (size_t)b * 2 * HH * WW;
    const float* g1 = g0 + (size_t)HH * WW;

    float p0 = node_pos[(b * NN + n) * 2 + 0];
    float p1 = node_pos[(b * NN + n) * 2 + 1];

    // pentadiagonal row of X for this node
    auto Dv = [](int i, int j) -> float {
        if (i < 0 || i >= NN || j < 0 || j >= NN) return 0.f;
        if (i == j) return (i == 0 || i == NN - 1) ? 1.f : 2.f;
        int d = i - j;
        if (d == 1 || d == -1) return -1.f;
        return 0.f;
    };
    float xc[5];
#pragma unroll
    for (int dj = -2; dj <= 2; ++dj) {
        int j = n + dj;
        float d2 = 0.f;
#pragma unroll
        for (int kk = -1; kk <= 1; ++kk) d2 += Dv(n, n + kk) * Dv(n + kk, j);
        xc[dj + 2] = 0.1f * (0.01f * Dv(n, j) + 0.01f * d2);
    }
    int jidx[5];
#pragma unroll
    for (int dj = -2; dj <= 2; ++dj) jidx[dj + 2] = min(max(n + dj, 0), NN - 1);

    __shared__ float sh[2][NN][2];
    int cur = 0;

    for (int step = 0; step < 20; ++step) {
        float f0 = bilerp_img(g0, p0, p1);
        float f1 = bilerp_img(g1, p0, p1);
        float q0 = p0 + 0.1f * f0;
        float q1 = p1 + 0.1f * f1;
        float s0 = q0, s1 = q1;
        sh[cur][n][0] = s0;
        sh[cur][n][1] = s1;
        __syncthreads();
#pragma unroll
        for (int it = 0; it < 4; ++it) {
            float a0 = 0.f, a1 = 0.f;
#pragma unroll
            for (int k = 0; k < 5; ++k) {
                a0 += xc[k] * sh[cur][jidx[k]][0];
                a1 += xc[k] * sh[cur][jidx[k]][1];
            }
            s0 = q0 - a0;
            s1 = q1 - a1;
            cur ^= 1;
            sh[cur][n][0] = s0;
            sh[cur][n][1] = s1;
            __syncthreads();
        }
        p0 = fminf(fmaxf(s0, 0.f), (float)(HH - 1));
        p1 = fminf(fmaxf(s1, 0.f), (float)(WW - 1));
    }
    pos_out[(b * NN + n) * 2 + 0] = p0;
    pos_out[(b * NN + n) * 2 + 1] = p1;
}

// ---------------- render distance map + MSE loss ----------------
__global__ __launch_bounds__(256) void render_loss_kernel(const float* __restrict__ pred,
                                                          const float* __restrict__ pos,
                                                          const float* __restrict__ widths,
                                                          float* __restrict__ out) {
    __shared__ float sp0[NN], sp1[NN], sw[NN];
    __shared__ float red[256];

    const int blk = blockIdx.x;          // NB*1024 blocks, 1024 per batch
    const int b = blk >> 10;
    const int rem = blk & 1023;
    const int t = threadIdx.x;

    sp0[t] = pos[(b * NN + t) * 2 + 0];
    sp1[t] = pos[(b * NN + t) * 2 + 1];
    sw[t]  = widths[b * NN + t];
    __syncthreads();

    const int pix = rem * 256 + t;       // linear pixel within batch image
    const float fy = (float)(pix >> 9);
    const float fx = (float)(pix & 511);

    float dm = 15.0f;
#pragma unroll 8
    for (int nn = 0; nn < NN; ++nn) {
        float dy = fy - sp0[nn];
        float dx = fx - sp1[nn];
        float d = sqrtf(dy * dy + dx * dx) - sw[nn];
        dm = fminf(dm, d);
    }
    dm = fminf(fmaxf(dm, 0.f), 15.0f);

    float pv = pred[(size_t)b * HH * WW + pix];
    float e = pv - dm;
    red[t] = e * e * (1.0f / (float)(NB * HH * WW));
    __syncthreads();
#pragma unroll
    for (int s = 128; s > 0; s >>= 1) {
        if (t < s) red[t] += red[t + s];
        __syncthreads();
    }
    if (t == 0) atomicAdd(out, red[0]);
}

extern "C" void kernel_launch(void* const* d_in, const int* in_sizes, int n_in,
                              void* d_out, int out_size, void* d_ws, size_t ws_size,
                              hipStream_t stream) {
    const float* pred     = (const float*)d_in[0];  // [8,1,512,512]
    const float* node_pos = (const float*)d_in[1];  // [8,256,2]
    const float* widths   = (const float*)d_in[2];  // [8,256]
    float* out = (float*)d_out;

    float* gimg    = (float*)d_ws;                          // [8][2][512][512] = 16 MB
    float* pos_out = gimg + (size_t)NB * 2 * HH * WW;       // [8][256][2]

    hipMemsetAsync(out, 0, sizeof(float), stream);

    dim3 cgrid(WW / 32, HH / 32, NB);
    conv_kernel<<<cgrid, 256, 0, stream>>>(pred, gimg);

    snake_kernel<<<NB, 256, 0, stream>>>(gimg, node_pos, pos_out);

    render_loss_kernel<<<NB * HH * WW / 256, 256, 0, stream>>>(pred, pos_out, widths, out);
}

// Round 3
// 102.855 us; speedup vs baseline: 3.7157x; 3.7157x over previous
//
#include <hip/hip_runtime.h>
#include <math.h>

#define HH 512
#define WW 512
#define NB 8
#define NN 256
#define KR 6
#define KS 13

__device__ __forceinline__ float bilerp_img(const float* __restrict__ img, float r, float c) {
    r = fminf(fmaxf(r, 0.f), (float)(HH - 1));
    c = fminf(fmaxf(c, 0.f), (float)(WW - 1));
    float rf = floorf(r), cf = floorf(c);
    int r0 = (int)rf, c0 = (int)cf;
    int r1 = min(r0 + 1, HH - 1), c1 = min(c0 + 1, WW - 1);
    float fr = r - rf, fc = c - cf;
    float v00 = img[r0 * WW + c0];
    float v01 = img[r0 * WW + c1];
    float v10 = img[r1 * WW + c0];
    float v11 = img[r1 * WW + c1];
    return v00 * (1.f - fr) * (1.f - fc) + v10 * fr * (1.f - fc)
         + v01 * (1.f - fr) * fc + v11 * fr * fc;
}

// ---------------- conv: separable 13x13 Gaussian-derivative, x10 ----------------
__global__ __launch_bounds__(256) void conv_kernel(const float* __restrict__ pred,
                                                   float* __restrict__ gimg) {
    __shared__ float tin[32 + 2 * KR][32 + 2 * KR];   // 44x44
    __shared__ float midG[32 + 2 * KR][32];
    __shared__ float midD[32 + 2 * KR][32];

    const int b  = blockIdx.z;
    const int ty0 = blockIdx.y * 32;
    const int tx0 = blockIdx.x * 32;
    const int t  = threadIdx.x;

    float g[KS], dg[KS];
    float s = 0.f;
#pragma unroll
    for (int i = 0; i < KS; ++i) {
        float x = (float)(i - KR);
        g[i] = expf(-x * x / 8.f);  // std=2 -> 2*std^2 = 8
        s += g[i];
    }
#pragma unroll
    for (int i = 0; i < KS; ++i) {
        g[i] /= s;
        dg[i] = (-(float)(i - KR) / 4.f) * g[i];
    }

    const float* img = pred + (size_t)b * HH * WW;

    for (int idx = t; idx < 44 * 44; idx += 256) {
        int ly = idx / 44, lx = idx % 44;
        int gy = ty0 + ly - KR, gx = tx0 + lx - KR;
        float v = 0.f;
        if (gy >= 0 && gy < HH && gx >= 0 && gx < WW) v = img[gy * WW + gx];
        tin[ly][lx] = v;
    }
    __syncthreads();

    for (int idx = t; idx < 44 * 32; idx += 256) {
        int ly = idx / 32, ox = idx % 32;
        float aG = 0.f, aD = 0.f;
#pragma unroll
        for (int k = 0; k < KS; ++k) {
            float v = tin[ly][ox + k];
            aG += v * g[k];
            aD += v * dg[k];
        }
        midG[ly][ox] = aG;
        midD[ly][ox] = aD;
    }
    __syncthreads();

    float* out0 = gimg + ((size_t)b * 2 + 0) * HH * WW;
    float* out1 = gimg + ((size_t)b * 2 + 1) * HH * WW;
    for (int idx = t; idx < 32 * 32; idx += 256) {
        int oy = idx / 32, ox = idx % 32;
        float a0 = 0.f, a1 = 0.f;
#pragma unroll
        for (int k = 0; k < KS; ++k) {
            a0 += midG[oy + k][ox] * dg[k];
            a1 += midD[oy + k][ox] * g[k];
        }
        int gy = ty0 + oy, gx = tx0 + ox;
        out0[gy * WW + gx] = 10.f * a0;
        out1[gy * WW + gx] = 10.f * a1;
    }
}

// ---------------- snake optimization: 20 implicit steps via Neumann series ----------------
__global__ __launch_bounds__(256) void snake_kernel(const float* __restrict__ gimg,
                                                    const float* __restrict__ node_pos,
                                                    float* __restrict__ pos_out) {
    const int b = blockIdx.x;
    const int n = threadIdx.x;
    const float* g0 = gimg + (size_t)b * 2 * HH * WW;
    const float* g1 = g0 + (size_t)HH * WW;

    float p0 = node_pos[(b * NN + n) * 2 + 0];
    float p1 = node_pos[(b * NN + n) * 2 + 1];

    auto Dv = [](int i, int j) -> float {
        if (i < 0 || i >= NN || j < 0 || j >= NN) return 0.f;
        if (i == j) return (i == 0 || i == NN - 1) ? 1.f : 2.f;
        int d = i - j;
        if (d == 1 || d == -1) return -1.f;
        return 0.f;
    };
    float xc[5];
#pragma unroll
    for (int dj = -2; dj <= 2; ++dj) {
        int j = n + dj;
        float d2 = 0.f;
#pragma unroll
        for (int kk = -1; kk <= 1; ++kk) d2 += Dv(n, n + kk) * Dv(n + kk, j);
        xc[dj + 2] = 0.1f * (0.01f * Dv(n, j) + 0.01f * d2);
    }
    int jidx[5];
#pragma unroll
    for (int dj = -2; dj <= 2; ++dj) jidx[dj + 2] = min(max(n + dj, 0), NN - 1);

    __shared__ float sh[2][NN][2];
    int cur = 0;

    for (int step = 0; step < 20; ++step) {
        float f0 = bilerp_img(g0, p0, p1);
        float f1 = bilerp_img(g1, p0, p1);
        float q0 = p0 + 0.1f * f0;
        float q1 = p1 + 0.1f * f1;
        float s0 = q0, s1 = q1;
        sh[cur][n][0] = s0;
        sh[cur][n][1] = s1;
        __syncthreads();
#pragma unroll
        for (int it = 0; it < 4; ++it) {
            float a0 = 0.f, a1 = 0.f;
#pragma unroll
            for (int k = 0; k < 5; ++k) {
                a0 += xc[k] * sh[cur][jidx[k]][0];
                a1 += xc[k] * sh[cur][jidx[k]][1];
            }
            s0 = q0 - a0;
            s1 = q1 - a1;
            cur ^= 1;
            sh[cur][n][0] = s0;
            sh[cur][n][1] = s1;
            __syncthreads();
        }
        p0 = fminf(fmaxf(s0, 0.f), (float)(HH - 1));
        p1 = fminf(fmaxf(s1, 0.f), (float)(WW - 1));
    }
    pos_out[(b * NN + n) * 2 + 0] = p0;
    pos_out[(b * NN + n) * 2 + 1] = p1;
}

// ---------------- render distance map + MSE loss (tile-binned) ----------------
// One block per 32x32 tile. Nodes can only affect pixels within 15+w, so
// compact the per-tile relevant node list first (fp-min is order-exact, so
// nondeterministic compaction order is safe).
__global__ __launch_bounds__(256) void render_loss_kernel(const float* __restrict__ pred,
                                                          const float* __restrict__ pos,
                                                          const float* __restrict__ widths,
                                                          float* __restrict__ out) {
    __shared__ float sl0[NN], sl1[NN], slw[NN];
    __shared__ int cnt;
    __shared__ float red[256];

    const int b    = blockIdx.x >> 8;        // 256 tiles (16x16) per batch
    const int tile = blockIdx.x & 255;
    const int ty0  = (tile >> 4) * 32;
    const int tx0  = (tile & 15) * 32;
    const int t    = threadIdx.x;

    if (t == 0) cnt = 0;
    __syncthreads();

    {   // node t relevance test against dilated tile box
        float p0 = pos[(b * NN + t) * 2 + 0];
        float p1 = pos[(b * NN + t) * 2 + 1];
        float w  = widths[b * NN + t];
        float dy = fmaxf(fmaxf((float)ty0 - p0, p0 - (float)(ty0 + 31)), 0.f);
        float dx = fmaxf(fmaxf((float)tx0 - p1, p1 - (float)(tx0 + 31)), 0.f);
        float rr = 15.f + w;
        if (dy * dy + dx * dx <= rr * rr) {
            int i = atomicAdd(&cnt, 1);
            sl0[i] = p0; sl1[i] = p1; slw[i] = w;
        }
    }
    __syncthreads();
    const int c = cnt;

    const float* pimg = pred + (size_t)b * HH * WW;
    float acc = 0.f;
#pragma unroll
    for (int i = 0; i < 4; ++i) {
        int idx = i * 256 + t;               // pixel within tile
        int oy = idx >> 5, ox = idx & 31;
        float fy = (float)(ty0 + oy);
        float fx = (float)(tx0 + ox);
        float dm = 15.0f;
        for (int j = 0; j < c; ++j) {
            float dy = fy - sl0[j];
            float dx = fx - sl1[j];
            float d = __builtin_amdgcn_sqrtf(dy * dy + dx * dx) - slw[j];
            dm = fminf(dm, d);
        }
        dm = fminf(fmaxf(dm, 0.f), 15.0f);
        float e = pimg[(ty0 + oy) * WW + (tx0 + ox)] - dm;
        acc += e * e;
    }

    red[t] = acc * (1.0f / (float)(NB * HH * WW));
    __syncthreads();
#pragma unroll
    for (int s = 128; s > 0; s >>= 1) {
        if (t < s) red[t] += red[t + s];
        __syncthreads();
    }
    if (t == 0) atomicAdd(out, red[0]);
}

extern "C" void kernel_launch(void* const* d_in, const int* in_sizes, int n_in,
                              void* d_out, int out_size, void* d_ws, size_t ws_size,
                              hipStream_t stream) {
    const float* pred     = (const float*)d_in[0];  // [8,1,512,512]
    const float* node_pos = (const float*)d_in[1];  // [8,256,2]
    const float* widths   = (const float*)d_in[2];  // [8,256]
    float* out = (float*)d_out;

    float* gimg    = (float*)d_ws;                          // [8][2][512][512] = 16 MB
    float* pos_out = gimg + (size_t)NB * 2 * HH * WW;       // [8][256][2]

    (void)hipMemsetAsync(out, 0, sizeof(float), stream);

    dim3 cgrid(WW / 32, HH / 32, NB);
    conv_kernel<<<cgrid, 256, 0, stream>>>(pred, gimg);

    snake_kernel<<<NB, 256, 0, stream>>>(gimg, node_pos, pos_out);

    render_loss_kernel<<<NB * 256, 256, 0, stream>>>(pred, pos_out, widths, out);
}